// Round 1
// baseline (781.563 us; speedup 1.0000x reference)
//
#include <hip/hip_runtime.h>
#include <math.h>

// Problem dims (fixed): T=4, B=8, C=128, H=W=56, mid=128.
#define T_ 4
#define B_ 8
#define C_ 128
#define H_ 56
#define W_ 56
#define NIMG (T_ * B_)              // 32 images for conv
#define HW (H_ * W_)                // 3136
#define NLOC (B_ * C_ * HW)         // 3211264 per-timestep elements
#define NE ((size_t)T_ * NLOC)      // 12845056 total elements
#define KTOT (C_ * 9)               // 1152 = K dimension of implicit GEMM
#define CI_BLK 8

// ---------------------------------------------------------------------------
// repack weights: w[co][ci][kh][kw] -> wt[(ci*9+tap)*128 + co]
// ---------------------------------------------------------------------------
__global__ void repack_w_k(const float* __restrict__ w, float* __restrict__ wt) {
    int i = blockIdx.x * 256 + threadIdx.x;
    if (i >= KTOT * C_) return;
    int k = i >> 7;        // 0..1151  (ci*9 + tap)
    int co = i & 127;
    wt[i] = w[(size_t)co * KTOT + k];
}

// ---------------------------------------------------------------------------
// conv3x3 SAME (128->128) + BN, one block per (image n, output row h)
// 256 threads = 32 co-groups (4 co each) x 8 px-groups (7 px each)
// ---------------------------------------------------------------------------
__global__ __launch_bounds__(256) void conv_bn_k(
        const float* __restrict__ in,      // [32][128][56][56]
        const float* __restrict__ wt,      // [1152][128]
        const float* __restrict__ gamma, const float* __restrict__ beta,
        const float* __restrict__ mean,  const float* __restrict__ var,
        float* __restrict__ out) {         // [32][128][56][56]
    int bid = blockIdx.x;
    int n = bid / H_;
    int h = bid - n * H_;
    const float* inN = in + (size_t)n * C_ * HW;

    __shared__ __align__(16) float ws_[CI_BLK * 9 * C_];   // [ci][tap][co] 36864B
    __shared__ float xs[CI_BLK][3][64];                    // rows h-1..h+1, col c = w+1, 6144B

    int tid = threadIdx.x;
    int co_grp = tid >> 3;           // 0..31
    int px_grp = tid & 7;            // 0..7
    int co0 = co_grp * 4;
    int w0 = px_grp * 7;

    float acc[4][7];
#pragma unroll
    for (int a = 0; a < 4; ++a)
#pragma unroll
        for (int b = 0; b < 7; ++b) acc[a][b] = 0.f;

    for (int ci0 = 0; ci0 < C_; ci0 += CI_BLK) {
        __syncthreads();   // protect previous iteration's LDS reads
        // stage weights: CI_BLK*9*128 = 9216 floats = 2304 float4, 9 per thread
        {
            const float4* src = (const float4*)(wt + (size_t)ci0 * 9 * C_);
            float4* dst = (float4*)ws_;
#pragma unroll
            for (int i = 0; i < 9; ++i) dst[tid + i * 256] = src[tid + i * 256];
        }
        // stage input slab: CI_BLK x 3 rows x 64 cols (58 valid, zero-padded)
#pragma unroll
        for (int it = 0; it < 6; ++it) {
            int i = tid + it * 256;              // 0..1535
            int ci = i / 192;
            int rem = i - ci * 192;
            int r = rem >> 6;
            int c = rem & 63;
            int hh = h + r - 1;
            int ww = c - 1;
            float v = 0.f;
            if (c < 58 && hh >= 0 && hh < H_ && ww >= 0 && ww < W_)
                v = inN[((size_t)(ci0 + ci) * H_ + hh) * W_ + ww];
            xs[ci][r][c] = v;
        }
        __syncthreads();

#pragma unroll
        for (int ci = 0; ci < CI_BLK; ++ci) {
            float xr[3][9];
#pragma unroll
            for (int r = 0; r < 3; ++r)
#pragma unroll
                for (int j = 0; j < 9; ++j)
                    xr[r][j] = xs[ci][r][w0 + j];
            const float* wp = ws_ + ci * 9 * C_;
#pragma unroll
            for (int t = 0; t < 9; ++t) {
                float4 wv = *(const float4*)(wp + t * C_ + co0);
                int r = t / 3, kw = t - (t / 3) * 3;
#pragma unroll
                for (int px = 0; px < 7; ++px) {
                    float xv = xr[r][px + kw];
                    acc[0][px] = fmaf(wv.x, xv, acc[0][px]);
                    acc[1][px] = fmaf(wv.y, xv, acc[1][px]);
                    acc[2][px] = fmaf(wv.z, xv, acc[2][px]);
                    acc[3][px] = fmaf(wv.w, xv, acc[3][px]);
                }
            }
        }
    }

    // epilogue: BN fold y = acc*inv + (beta - mean*inv)
#pragma unroll
    for (int ii = 0; ii < 4; ++ii) {
        int co = co0 + ii;
        float inv = gamma[co] / sqrtf(var[co] + 1e-5f);
        float bias = beta[co] - mean[co] * inv;
        float* op = out + (((size_t)n * C_ + co) * H_ + h) * W_ + w0;
#pragma unroll
        for (int px = 0; px < 7; ++px) op[px] = fmaf(acc[ii][px], inv, bias);
    }
}

// ---------------------------------------------------------------------------
// PLIF scan over T: v += (x-v)*sigmoid(w); spike = v>=1; hard reset to 0
// ---------------------------------------------------------------------------
__global__ __launch_bounds__(256) void plif_k(
        const float* __restrict__ y, const float* __restrict__ wparam,
        float* __restrict__ s_out) {
    int i = blockIdx.x * 256 + threadIdx.x;
    if (i >= NLOC) return;
    float k = 1.f / (1.f + expf(-wparam[0]));
    float v = 0.f;
#pragma unroll
    for (int t = 0; t < T_; ++t) {
        float x = y[(size_t)t * NLOC + i];
        v = v + (x - v) * k;
        float s = (v >= 1.0f) ? 1.0f : 0.0f;
        s_out[(size_t)t * NLOC + i] = s;
        v = (v >= 1.0f) ? 0.f : v;
    }
}

// PLIF + residual add: out = spike + x_in
__global__ __launch_bounds__(256) void plif_add_k(
        const float* __restrict__ y, const float* __restrict__ wparam,
        const float* __restrict__ x_in, float* __restrict__ out) {
    int i = blockIdx.x * 256 + threadIdx.x;
    if (i >= NLOC) return;
    float k = 1.f / (1.f + expf(-wparam[0]));
    float v = 0.f;
#pragma unroll
    for (int t = 0; t < T_; ++t) {
        size_t idx = (size_t)t * NLOC + i;
        float x = y[idx];
        v = v + (x - v) * k;
        float s = (v >= 1.0f) ? 1.0f : 0.0f;
        out[idx] = s + x_in[idx];
        v = (v >= 1.0f) ? 0.f : v;
    }
}

// ---------------------------------------------------------------------------
extern "C" void kernel_launch(void* const* d_in, const int* in_sizes, int n_in,
                              void* d_out, int out_size, void* d_ws, size_t ws_size,
                              hipStream_t stream) {
    const float* x    = (const float*)d_in[0];
    const float* w1   = (const float*)d_in[1];
    const float* g1   = (const float*)d_in[2];
    const float* be1  = (const float*)d_in[3];
    const float* mu1  = (const float*)d_in[4];
    const float* va1  = (const float*)d_in[5];
    const float* tau1 = (const float*)d_in[6];
    const float* w2   = (const float*)d_in[7];
    const float* g2   = (const float*)d_in[8];
    const float* be2  = (const float*)d_in[9];
    const float* mu2  = (const float*)d_in[10];
    const float* va2  = (const float*)d_in[11];
    const float* tau2 = (const float*)d_in[12];
    float* out = (float*)d_out;

    float* ws  = (float*)d_ws;
    float* A   = ws;                     // [NE] conv output buffer (reused)
    float* S1  = ws + NE;                // [NE] layer-1 spikes
    float* w1t = ws + 2 * NE;            // [1152*128] repacked weights
    float* w2t = w1t + KTOT * C_;

    int rp_grid = (KTOT * C_ + 255) / 256;
    repack_w_k<<<rp_grid, 256, 0, stream>>>(w1, w1t);
    repack_w_k<<<rp_grid, 256, 0, stream>>>(w2, w2t);

    int conv_grid = NIMG * H_;           // 1792
    int pw_grid = NLOC / 256;            // 12544

    conv_bn_k<<<conv_grid, 256, 0, stream>>>(x, w1t, g1, be1, mu1, va1, A);
    plif_k<<<pw_grid, 256, 0, stream>>>(A, tau1, S1);
    conv_bn_k<<<conv_grid, 256, 0, stream>>>(S1, w2t, g2, be2, mu2, va2, A);
    plif_add_k<<<pw_grid, 256, 0, stream>>>(A, tau2, x, out);
}

// Round 2
// 249.203 us; speedup vs baseline: 3.1362x; 3.1362x over previous
//
#include <hip/hip_runtime.h>
#include <math.h>

// Dims fixed: T=4, B=8, C=128, H=W=56, mid=128.
#define T_ 4
#define B_ 8
#define C_ 128
#define H_ 56
#define W_ 56
#define NIMG (T_ * B_)              // 32
#define HW (H_ * W_)                // 3136
#define NLOC ((size_t)B_ * C_ * HW) // 3211264 per-t elements
#define NE ((size_t)T_ * NLOC)      // 12845056

typedef __attribute__((ext_vector_type(8))) short short8v;   // bf16x8 frag
typedef __attribute__((ext_vector_type(4))) float float4v;   // fp32x4 acc

__device__ __forceinline__ unsigned short f2bf(float f) {
    unsigned u = __float_as_uint(f);
    unsigned r = u + 0x7fffu + ((u >> 16) & 1u);   // RNE
    return (unsigned short)(r >> 16);
}
__device__ __forceinline__ float bf2f(unsigned short h) {
    return __uint_as_float(((unsigned)h) << 16);
}

#define GLOAD_LDS16(gp, lp) \
    __builtin_amdgcn_global_load_lds((const __attribute__((address_space(1))) unsigned int*)(gp), \
                                     (__attribute__((address_space(3))) unsigned int*)(lp), 16, 0, 0)

// ---------------------------------------------------------------------------
// repack weights into 3-way bf16 split, MFMA/B-frag layout, XOR-swizzled:
// tile s = tap*3+spl (32KB each); within tile byte = co*256 + ((ci>>3)^(co&7))*16 + (ci&7)*2
// ---------------------------------------------------------------------------
__global__ __launch_bounds__(256) void repack_k(const float* __restrict__ w,
                                                unsigned short* __restrict__ Bs) {
    int i = blockIdx.x * 256 + threadIdx.x;       // (tap, co, slot)
    if (i >= 9 * 128 * 16) return;
    int tap = i / 2048;
    int rem = i - tap * 2048;
    int co = rem >> 4, slot = rem & 15;
    short8v h1, h2, h3;
#pragma unroll
    for (int e = 0; e < 8; ++e) {
        int ci = slot * 8 + e;
        float v = w[((size_t)co * 128 + ci) * 9 + tap];
        unsigned short a = f2bf(v);
        float r1 = v - bf2f(a);
        unsigned short b = f2bf(r1);
        float r2 = r1 - bf2f(b);
        unsigned short c = f2bf(r2);
        h1[e] = (short)a; h2[e] = (short)b; h3[e] = (short)c;
    }
    int slotp = slot ^ (co & 7);
    size_t base = (size_t)tap * 3 * 16384 + (size_t)co * 128 + slotp * 8;
    *(short8v*)(Bs + base)             = h1;
    *(short8v*)(Bs + base + 16384)     = h2;
    *(short8v*)(Bs + base + 2 * 16384) = h3;
}

// ---------------------------------------------------------------------------
// x fp32 NCHW -> Xt bf16 NHWC  (one block per (n,h))
// ---------------------------------------------------------------------------
__global__ __launch_bounds__(256) void xpose_k(const float* __restrict__ x,
                                               unsigned short* __restrict__ Xt) {
    __shared__ float xs[128][57];
    int n = blockIdx.x / 56, h = blockIdx.x % 56;
    int tid = threadIdx.x;
    const float* xp = x + (size_t)n * 128 * HW + h * 56;
#pragma unroll
    for (int j = 0; j < 7; ++j) {
        int idx = tid + j * 256;              // 0..1791
        int c = idx / 14, wq = idx - c * 14;
        float4 v = *(const float4*)(xp + (size_t)c * HW + wq * 4);
        xs[c][wq * 4 + 0] = v.x; xs[c][wq * 4 + 1] = v.y;
        xs[c][wq * 4 + 2] = v.z; xs[c][wq * 4 + 3] = v.w;
    }
    __syncthreads();
    unsigned* Op = (unsigned*)(Xt + ((size_t)n * HW + h * 56) * 128);
#pragma unroll
    for (int j = 0; j < 14; ++j) {
        int idx = tid + j * 256;              // 0..3583 = w*64 + cpair
        int ww = idx >> 6, cp = idx & 63;
        unsigned lo = f2bf(xs[2 * cp][ww]);
        unsigned hi = f2bf(xs[2 * cp + 1][ww]);
        Op[idx] = lo | (hi << 16);
    }
}

// ---------------------------------------------------------------------------
// conv3x3 SAME + BN via MFMA implicit GEMM.
// Block: 256 thr / 4 waves. Tile: 4 rows x 64 px x 128 co. 27 stages (9 tap x 3 split),
// B double-buffered in LDS via global_load_lds, counted vmcnt.
// ---------------------------------------------------------------------------
__global__ __launch_bounds__(256, 2) void conv_mfma_k(
        const unsigned short* __restrict__ Xt,     // bf16 NHWC [32][56][56][128]
        const unsigned short* __restrict__ Bs,     // 27 x 32KB swizzled tiles
        const float* __restrict__ gamma, const float* __restrict__ beta,
        const float* __restrict__ mean,  const float* __restrict__ var,
        float* __restrict__ Y) {                   // fp32 NHWC
    __shared__ unsigned short bls[2][16384];
    const int tid = threadIdx.x;
    const int lane = tid & 63;
    const int wave = tid >> 6;
    const int fr = lane & 15, fq = lane >> 4;
    const int img = blockIdx.x / 14;
    const int h = (blockIdx.x % 14) * 4 + wave;    // this wave's output row
    const unsigned short* XtN = Xt + (size_t)img * HW * 128;

    float4v acc[4][8];
#pragma unroll
    for (int m = 0; m < 4; ++m)
#pragma unroll
        for (int nf = 0; nf < 8; ++nf) acc[m][nf] = (float4v){0.f, 0.f, 0.f, 0.f};

    short8v a[4][4];
    const short8v zero8 = (short8v){0, 0, 0, 0, 0, 0, 0, 0};

#define STAGE(sidx, buf) do {                                                   \
        const char* _src = (const char*)Bs + (size_t)(sidx) * 32768 + tid * 16; \
        char* _dst = (char*)&bls[(buf)][0] + tid * 16;                          \
        _Pragma("unroll")                                                       \
        for (int _i = 0; _i < 8; ++_i)                                          \
            GLOAD_LDS16(_src + _i * 4096, _dst + _i * 4096);                    \
    } while (0)

#define LOADA(tap) do {                                                         \
        int _dh = (tap) / 3, _dw = (tap) % 3;                                   \
        int _hh = h + _dh - 1;                                                  \
        bool _hok = (unsigned)_hh < 56u;                                        \
        _Pragma("unroll")                                                       \
        for (int _m = 0; _m < 4; ++_m) {                                        \
            int _w = _m * 16 + fr + _dw - 1;                                    \
            bool _ok = _hok && ((unsigned)_w < 56u);                            \
            size_t _el = _ok ? ((size_t)(_hh * 56 + _w) * 128) : 0;             \
            const short8v* _p = (const short8v*)(XtN + _el);                    \
            _Pragma("unroll")                                                   \
            for (int _kk = 0; _kk < 4; ++_kk) {                                 \
                short8v _v = _p[_kk * 4 + fq];                                  \
                a[_m][_kk] = _ok ? _v : zero8;                                  \
            }                                                                   \
        }                                                                       \
    } while (0)

    // prologue
    STAGE(0, 0);
    LOADA(0);
    asm volatile("s_waitcnt vmcnt(0)" ::: "memory");
    __builtin_amdgcn_sched_barrier(0);
    __builtin_amdgcn_s_barrier();

    for (int s = 0; s < 27; ++s) {
        const int cur = s & 1;
        if (s < 26) {
            STAGE(s + 1, cur ^ 1);
            asm volatile("s_waitcnt vmcnt(8)" ::: "memory");   // STAGE(s)+A drained, STAGE(s+1) in flight
        } else {
            asm volatile("s_waitcnt vmcnt(0)" ::: "memory");
        }
        __builtin_amdgcn_sched_barrier(0);
        __builtin_amdgcn_s_barrier();

        const char* bp = (const char*)&bls[cur][0];
#pragma unroll
        for (int kk = 0; kk < 4; ++kk) {
            short8v b[8];
            int bb = fr * 256 + (((kk * 4 + fq) ^ (fr & 7)) << 4);
#pragma unroll
            for (int nf = 0; nf < 8; ++nf)
                b[nf] = *(const short8v*)(bp + bb + nf * 4096);
#pragma unroll
            for (int m = 0; m < 4; ++m)
#pragma unroll
                for (int nf = 0; nf < 8; ++nf)
                    acc[m][nf] = __builtin_amdgcn_mfma_f32_16x16x32_bf16(
                        a[m][kk], b[nf], acc[m][nf], 0, 0, 0);
        }
        if ((s % 3) == 2 && s < 26) LOADA(s / 3 + 1);   // prefetch next tap's A (regs free now)
        asm volatile("s_waitcnt lgkmcnt(0)" ::: "memory");
        __builtin_amdgcn_sched_barrier(0);
        __builtin_amdgcn_s_barrier();                   // buf[cur] safe to overwrite next iter
    }

    // epilogue: BN + store (Y NHWC fp32)
    float invv[8], bias[8];
#pragma unroll
    for (int nf = 0; nf < 8; ++nf) {
        int co = nf * 16 + fr;
        float iv = gamma[co] / sqrtf(var[co] + 1e-5f);
        invv[nf] = iv;
        bias[nf] = beta[co] - mean[co] * iv;
    }
    float* Yp = Y + ((size_t)img * HW + h * 56) * 128;
#pragma unroll
    for (int m = 0; m < 4; ++m)
#pragma unroll
        for (int r = 0; r < 4; ++r) {
            int ww = m * 16 + fq * 4 + r;
            if (ww < 56) {
                float* row = Yp + (size_t)ww * 128;
#pragma unroll
                for (int nf = 0; nf < 8; ++nf)
                    row[nf * 16 + fr] = fmaf(acc[m][nf][r], invv[nf], bias[nf]);
            }
        }
#undef STAGE
#undef LOADA
}

// ---------------------------------------------------------------------------
// PLIF over T on NHWC fp32 -> bf16 spikes (layer 1)
// ---------------------------------------------------------------------------
__global__ __launch_bounds__(256) void plif1_k(const float* __restrict__ Y,
                                               const float* __restrict__ wp,
                                               unsigned short* __restrict__ S) {
    size_t i4 = ((size_t)blockIdx.x * 256 + threadIdx.x) * 4;
    float k = 1.f / (1.f + expf(-wp[0]));
    float v0 = 0.f, v1 = 0.f, v2 = 0.f, v3 = 0.f;
#pragma unroll
    for (int t = 0; t < 4; ++t) {
        float4 xv = *(const float4*)(Y + (size_t)t * NLOC + i4);
        v0 = v0 + (xv.x - v0) * k;
        v1 = v1 + (xv.y - v1) * k;
        v2 = v2 + (xv.z - v2) * k;
        v3 = v3 + (xv.w - v3) * k;
        ushort4 sv;
        sv.x = (v0 >= 1.f) ? 0x3F80 : 0;  v0 = (v0 >= 1.f) ? 0.f : v0;
        sv.y = (v1 >= 1.f) ? 0x3F80 : 0;  v1 = (v1 >= 1.f) ? 0.f : v1;
        sv.z = (v2 >= 1.f) ? 0x3F80 : 0;  v2 = (v2 >= 1.f) ? 0.f : v2;
        sv.w = (v3 >= 1.f) ? 0x3F80 : 0;  v3 = (v3 >= 1.f) ? 0.f : v3;
        *(ushort4*)(S + (size_t)t * NLOC + i4) = sv;
    }
}

// ---------------------------------------------------------------------------
// PLIF layer 2 + residual, NHWC fp32 -> NCHW fp32 out (LDS transpose)
// block = (b, h, c-half)
// ---------------------------------------------------------------------------
__global__ __launch_bounds__(256) void plif2_k(const float* __restrict__ Y2,
                                               const float* __restrict__ wp,
                                               const float* __restrict__ x,
                                               float* __restrict__ out) {
    __shared__ float xs[4 * 56 * 65];
    int bid = blockIdx.x;
    int half = bid & 1;
    int bh = bid >> 1;
    int b = bh / 56, h = bh % 56;
    int tid = threadIdx.x;
    float k = 1.f / (1.f + expf(-wp[0]));
#pragma unroll
    for (int j = 0; j < 14; ++j) {
        int idx = tid + j * 256;              // 0..3583
        int t = idx / 896;
        int rem = idx - t * 896;
        int ww = rem >> 4, cq = rem & 15;
        float4 v = *(const float4*)(Y2 + ((size_t)(t * 8 + b) * HW + h * 56 + ww) * 128
                                       + half * 64 + cq * 4);
        float* dst = &xs[(t * 56 + ww) * 65 + cq * 4];
        dst[0] = v.x; dst[1] = v.y; dst[2] = v.z; dst[3] = v.w;
    }
    __syncthreads();
#pragma unroll
    for (int j = 0; j < 14; ++j) {
        int idx = tid + j * 256;              // c*56 + w
        int c = idx / 56, ww = idx - c * 56;
        float v = 0.f;
        size_t xo = ((size_t)b * 128 + half * 64 + c) * HW + h * 56 + ww;
#pragma unroll
        for (int t = 0; t < 4; ++t) {
            float yv = xs[(t * 56 + ww) * 65 + c];
            v = v + (yv - v) * k;
            bool sp = v >= 1.f;
            size_t o = xo + (size_t)t * NLOC;
            out[o] = (sp ? 1.f : 0.f) + x[o];
            v = sp ? 0.f : v;
        }
    }
}

// ---------------------------------------------------------------------------
extern "C" void kernel_launch(void* const* d_in, const int* in_sizes, int n_in,
                              void* d_out, int out_size, void* d_ws, size_t ws_size,
                              hipStream_t stream) {
    const float* x    = (const float*)d_in[0];
    const float* w1   = (const float*)d_in[1];
    const float* g1   = (const float*)d_in[2];
    const float* be1  = (const float*)d_in[3];
    const float* mu1  = (const float*)d_in[4];
    const float* va1  = (const float*)d_in[5];
    const float* tau1 = (const float*)d_in[6];
    const float* w2   = (const float*)d_in[7];
    const float* g2   = (const float*)d_in[8];
    const float* be2  = (const float*)d_in[9];
    const float* mu2  = (const float*)d_in[10];
    const float* va2  = (const float*)d_in[11];
    const float* tau2 = (const float*)d_in[12];
    float* out = (float*)d_out;

    char* ws = (char*)d_ws;
    unsigned short* bufA = (unsigned short*)ws;            // bf16 [NE]: Xt, then S1
    float* bufY = (float*)(ws + NE * 2);                   // fp32 [NE]: Y1, then Y2
    unsigned short* Bs1 = (unsigned short*)(ws + NE * 6);
    unsigned short* Bs2 = Bs1 + 27 * 16384;

    repack_k<<<72, 256, 0, stream>>>(w1, Bs1);
    repack_k<<<72, 256, 0, stream>>>(w2, Bs2);
    xpose_k<<<NIMG * 56, 256, 0, stream>>>(x, bufA);

    conv_mfma_k<<<NIMG * 14, 256, 0, stream>>>(bufA, Bs1, g1, be1, mu1, va1, bufY);
    plif1_k<<<(int)(NLOC / 1024), 256, 0, stream>>>(bufY, tau1, bufA);
    conv_mfma_k<<<NIMG * 14, 256, 0, stream>>>(bufA, Bs2, g2, be2, mu2, va2, bufY);
    plif2_k<<<B_ * 56 * 2, 256, 0, stream>>>(bufY, tau2, x, out);
}

// Round 3
// 217.126 us; speedup vs baseline: 3.5996x; 1.1477x over previous
//
#include <hip/hip_runtime.h>
#include <math.h>

// Dims fixed: T=4, B=8, C=128, H=W=56, mid=128.
#define T_ 4
#define B_ 8
#define C_ 128
#define H_ 56
#define W_ 56
#define NIMG (T_ * B_)              // 32
#define HW (H_ * W_)                // 3136
#define NLOC ((size_t)B_ * C_ * HW) // 3211264 per-t elements
#define NE ((size_t)T_ * NLOC)      // 12845056

typedef __attribute__((ext_vector_type(4))) int   int4v;
typedef __attribute__((ext_vector_type(4))) float float4v;

#define GLOAD_LDS16(gp, lp) \
    __builtin_amdgcn_global_load_lds((const __attribute__((address_space(1))) unsigned int*)(gp), \
                                     (__attribute__((address_space(3))) unsigned int*)(lp), 16, 0, 0)

// ---------------------------------------------------------------------------
// per-co scale: sv[co] = max_{ci,tap}|w[co][ci][tap]| / 127
// ---------------------------------------------------------------------------
__global__ __launch_bounds__(128) void scale_k(const float* __restrict__ w,
                                               float* __restrict__ sv) {
    __shared__ float red[128];
    int co = blockIdx.x, t = threadIdx.x;
    const float* p = w + (size_t)co * 1152 + t * 9;
    float m = 0.f;
#pragma unroll
    for (int j = 0; j < 9; ++j) m = fmaxf(m, fabsf(p[j]));
    red[t] = m; __syncthreads();
    for (int off = 64; off; off >>= 1) {
        if (t < off) red[t] = fmaxf(red[t], red[t + off]);
        __syncthreads();
    }
    if (t == 0) sv[co] = fmaxf(red[0], 1e-20f) / 127.f;
}

// ---------------------------------------------------------------------------
// repack weights -> 27 i8 tiles of 16KB. stage = tap*3 + split.
// tile byte L(co,ci) = co*128 + ((ci>>4 ^ (co&7))<<4) + (ci&15)
// 3-way split: w = s*(q1 + q2/128 + q3/16384), exact-int accumulation later.
// ---------------------------------------------------------------------------
__global__ __launch_bounds__(256) void repack_k(const float* __restrict__ w,
                                                const float* __restrict__ sv,
                                                signed char* __restrict__ Bs) {
    int idx = blockIdx.x * 256 + threadIdx.x;
    if (idx >= 9 * 1024) return;
    int tap = idx >> 10;
    int rem = idx & 1023;
    int co = rem >> 3, cig = rem & 7;
    double s = (double)sv[co];
    union { signed char b[16]; int4v v; } q[3];
#pragma unroll
    for (int e = 0; e < 16; ++e) {
        int ci = cig * 16 + e;
        double v = (double)w[((size_t)co * 128 + ci) * 9 + tap];
        double q1 = rint(v / s);
        double r1 = v - s * q1;
        double q2 = rint(r1 * 128.0 / s);
        double r2 = r1 - s * q2 * 0.0078125;
        double q3 = rint(r2 * 16384.0 / s);
        q[0].b[e] = (signed char)(int)q1;
        q[1].b[e] = (signed char)(int)q2;
        q[2].b[e] = (signed char)(int)q3;
    }
    int Lb = co * 128 + ((cig ^ (co & 7)) << 4);
#pragma unroll
    for (int sp = 0; sp < 3; ++sp)
        *(int4v*)(Bs + (size_t)(tap * 3 + sp) * 16384 + Lb) = q[sp].v;
}

// ---------------------------------------------------------------------------
// x fp32 NCHW -> Xt i8 NHWC, ci-slot XOR-swizzled by (w&7):
// byte at px*128 + slot*16 + b holds ci = (slot ^ (px&7))*16 + b
// ---------------------------------------------------------------------------
__global__ __launch_bounds__(256) void xpose_k(const float* __restrict__ x,
                                               signed char* __restrict__ Xt) {
    __shared__ float xs[128][57];
    int n = blockIdx.x / 56, h = blockIdx.x % 56;
    int tid = threadIdx.x;
    const float* xp = x + (size_t)n * 128 * HW + h * 56;
#pragma unroll
    for (int j = 0; j < 7; ++j) {
        int idx = tid + j * 256;              // 0..1791 = c*14 + wq
        int c = idx / 14, wq = idx - c * 14;
        float4 v = *(const float4*)(xp + (size_t)c * HW + wq * 4);
        xs[c][wq * 4 + 0] = v.x; xs[c][wq * 4 + 1] = v.y;
        xs[c][wq * 4 + 2] = v.z; xs[c][wq * 4 + 3] = v.w;
    }
    __syncthreads();
    signed char* Op = Xt + ((size_t)n * HW + h * 56) * 128;
#pragma unroll
    for (int j = 0; j < 2; ++j) {
        int idx = tid + j * 256;              // 0..447 = ww*8 + slot
        if (idx < 448) {
            int ww = idx >> 3, sl = idx & 7;
            int cg = sl ^ (ww & 7);
            union { signed char b[16]; int4v v; } u;
#pragma unroll
            for (int e = 0; e < 16; ++e)
                u.b[e] = (xs[cg * 16 + e][ww] >= 0.5f) ? 1 : 0;
            *(int4v*)(Op + ww * 128 + sl * 16) = u.v;
        }
    }
}

// ---------------------------------------------------------------------------
// conv3x3 SAME + BN, i8 MFMA implicit GEMM.
// Block: 512 thr / 8 waves = 2 rows x 4 co-quarters. Wave: 64px x 32co.
// A: 4 rows staged once in LDS (32KB, swizzled). B: 27 x 16KB tiles,
// double-buffered via global_load_lds, counted vmcnt.
// ---------------------------------------------------------------------------
__global__ __launch_bounds__(512, 4) void conv_mfma_k(
        const signed char* __restrict__ Xt,   // i8 NHWC swizzled [32][3136][128]
        const signed char* __restrict__ Bs,   // 27 x 16KB tiles
        const float* __restrict__ sv,
        const float* __restrict__ gamma, const float* __restrict__ beta,
        const float* __restrict__ mean,  const float* __restrict__ var,
        float* __restrict__ Y) {              // fp32 NHWC
    __shared__ signed char aA[32768];         // 4 rows x 64px x 128ci
    __shared__ signed char bB[2][16384];

    const int tid = threadIdx.x;
    const int lane = tid & 63;
    const int wave = tid >> 6;
    const int fr = lane & 15, fq = lane >> 4;
    const int row_local = wave >> 2;          // 0..1
    const int quarter = wave & 3;             // 0..3
    const int img = blockIdx.x / 28;
    const int h0 = (blockIdx.x % 28) * 2;
    const int h = h0 + row_local;

    const float sc0 = sv[quarter * 32 + fr];
    const float sc1 = sv[quarter * 32 + 16 + fr];

    float4v accf[4][2];
#pragma unroll
    for (int m = 0; m < 4; ++m) {
        accf[m][0] = (float4v){0.f, 0.f, 0.f, 0.f};
        accf[m][1] = (float4v){0.f, 0.f, 0.f, 0.f};
    }
    int4v a[4][2];
    const int4v zi = (int4v){0, 0, 0, 0};

#define STAGEB(sidx, buf) do {                                                    \
        const char* _src = (const char*)Bs + (size_t)(sidx) * 16384 + tid * 16;   \
        char* _dst = (char*)&bB[(buf)][0] + tid * 16;                             \
        GLOAD_LDS16(_src, _dst);                                                  \
        GLOAD_LDS16(_src + 8192, _dst + 8192);                                    \
    } while (0)

#define LOADA(tap) do {                                                           \
        int _dh = (tap) / 3, _dw = (tap) % 3;                                     \
        int _hh = h + _dh - 1;                                                    \
        bool _hok = (unsigned)_hh < 56u;                                          \
        int _r4 = row_local + _dh;                                                \
        _Pragma("unroll")                                                         \
        for (int _m = 0; _m < 4; ++_m) {                                          \
            int _px = _m * 16 + fr + _dw - 1;                                     \
            bool _ok = _hok && ((unsigned)_px < 56u);                             \
            int _pxc = _ok ? _px : 0;                                             \
            const signed char* _base = aA + _r4 * 8192 + _pxc * 128;              \
            _Pragma("unroll")                                                     \
            for (int _ks = 0; _ks < 2; ++_ks) {                                   \
                int _sl = (_ks * 4 + fq) ^ (_pxc & 7);                            \
                int4v _v = *(const int4v*)(_base + _sl * 16);                     \
                a[_m][_ks] = _ok ? _v : zi;                                       \
            }                                                                     \
        }                                                                         \
    } while (0)

    // prologue: stage A (4 rows) + B tile 0
    {
        const signed char* XtN = Xt + (size_t)img * HW * 128;
#pragma unroll
        for (int i = 0; i < 4; ++i) {
            int hh = h0 - 1 + i;
            hh = hh < 0 ? 0 : (hh > 55 ? 55 : hh);    // clamp (reads masked later)
            const char* src = (const char*)(XtN + (size_t)hh * 56 * 128) + tid * 16;
            char* dst = (char*)aA + i * 8192 + tid * 16;
            GLOAD_LDS16(src, dst);
        }
        STAGEB(0, 0);
        asm volatile("s_waitcnt vmcnt(0)" ::: "memory");
        __builtin_amdgcn_sched_barrier(0);
        __builtin_amdgcn_s_barrier();
    }
    LOADA(0);

    for (int s = 0; s < 27; ++s) {
        const int cur = s & 1;
        if (s < 26) {
            STAGEB(s + 1, cur ^ 1);
            asm volatile("s_waitcnt vmcnt(2)" ::: "memory");  // STAGE(s) done; (s+1) in flight
        } else {
            asm volatile("s_waitcnt vmcnt(0)" ::: "memory");
        }
        __builtin_amdgcn_sched_barrier(0);
        __builtin_amdgcn_s_barrier();

        const signed char* bp = &bB[cur][0];
        int4v t[4][2];
#pragma unroll
        for (int ks = 0; ks < 2; ++ks) {
            int co_b = (quarter * 32 + fr) * 128;
            int sl = ((ks * 4 + fq) ^ (fr & 7)) << 4;
            int4v b0 = *(const int4v*)(bp + co_b + sl);
            int4v b1 = *(const int4v*)(bp + co_b + 16 * 128 + sl);
#pragma unroll
            for (int m = 0; m < 4; ++m) {
                t[m][0] = __builtin_amdgcn_mfma_i32_16x16x64_i8(a[m][ks], b0,
                            ks ? t[m][0] : zi, 0, 0, 0);
                t[m][1] = __builtin_amdgcn_mfma_i32_16x16x64_i8(a[m][ks], b1,
                            ks ? t[m][1] : zi, 0, 0, 0);
            }
        }
        // fold int acc -> float acc with per-co scale * split weight
        int split = s - (s / 3) * 3;
        float mc = (split == 0) ? 1.0f : (split == 1 ? 0.0078125f : 6.103515625e-05f);
        float m0 = sc0 * mc, m1 = sc1 * mc;
#pragma unroll
        for (int m = 0; m < 4; ++m)
#pragma unroll
            for (int e = 0; e < 4; ++e) {
                accf[m][0][e] = fmaf(m0, (float)t[m][0][e], accf[m][0][e]);
                accf[m][1][e] = fmaf(m1, (float)t[m][1][e], accf[m][1][e]);
            }
        if (split == 2 && s < 26) LOADA(s / 3 + 1);
        asm volatile("s_waitcnt lgkmcnt(0)" ::: "memory");
        __builtin_amdgcn_sched_barrier(0);
        __builtin_amdgcn_s_barrier();
    }

    // epilogue: BN + store, Y NHWC fp32
    float* Yp = Y + ((size_t)img * HW + h * 56) * 128;
#pragma unroll
    for (int nf = 0; nf < 2; ++nf) {
        int co = quarter * 32 + nf * 16 + fr;
        float iv = gamma[co] / sqrtf(var[co] + 1e-5f);
        float bs = beta[co] - mean[co] * iv;
#pragma unroll
        for (int m = 0; m < 4; ++m)
#pragma unroll
            for (int r = 0; r < 4; ++r) {
                int ww = m * 16 + fq * 4 + r;
                if (ww < 56)
                    Yp[(size_t)ww * 128 + co] = fmaf(accf[m][nf][r], iv, bs);
            }
    }
#undef STAGEB
#undef LOADA
}

// ---------------------------------------------------------------------------
// PLIF layer1: Y fp32 NHWC -> spikes i8 NHWC (swizzled, conv2 input)
// thread = (b, hw, cig): 16 channels, recurrence over T in regs
// ---------------------------------------------------------------------------
__global__ __launch_bounds__(256) void plif1_k(const float* __restrict__ Y,
                                               const float* __restrict__ wp,
                                               signed char* __restrict__ S) {
    int gid = blockIdx.x * 256 + threadIdx.x;     // 0..200703
    int cg = gid & 7;
    int pix = gid >> 3;                           // b*3136 + hw
    int w = (pix % HW) % 56;
    float k = 1.f / (1.f + expf(-wp[0]));
    float v[16];
#pragma unroll
    for (int e = 0; e < 16; ++e) v[e] = 0.f;
    size_t base = (size_t)pix * 128 + cg * 16;
    size_t obase = (size_t)pix * 128 + ((cg ^ (w & 7)) << 4);
#pragma unroll
    for (int t = 0; t < 4; ++t) {
        const float* yp = Y + (size_t)t * NLOC + base;
        union { signed char b[16]; int4v iv; } u;
#pragma unroll
        for (int e4 = 0; e4 < 4; ++e4) {
            float4 xv = *(const float4*)(yp + e4 * 4);
            float xe[4] = {xv.x, xv.y, xv.z, xv.w};
#pragma unroll
            for (int j = 0; j < 4; ++j) {
                int e = e4 * 4 + j;
                v[e] = v[e] + (xe[j] - v[e]) * k;
                bool sp = v[e] >= 1.f;
                u.b[e] = sp ? 1 : 0;
                v[e] = sp ? 0.f : v[e];
            }
        }
        *(int4v*)(S + (size_t)t * NLOC + obase) = u.iv;
    }
}

// ---------------------------------------------------------------------------
// PLIF layer2 + residual: Y2 fp32 NHWC + x fp32 NCHW -> out fp32 NCHW
// ---------------------------------------------------------------------------
__global__ __launch_bounds__(256) void plif2_k(const float* __restrict__ Y2,
                                               const float* __restrict__ wp,
                                               const float* __restrict__ x,
                                               float* __restrict__ out) {
    __shared__ float xs[4 * 56 * 65];
    int bid = blockIdx.x;
    int half = bid & 1;
    int bh = bid >> 1;
    int b = bh / 56, h = bh % 56;
    int tid = threadIdx.x;
    float k = 1.f / (1.f + expf(-wp[0]));
#pragma unroll
    for (int j = 0; j < 14; ++j) {
        int idx = tid + j * 256;              // 0..3583
        int t = idx / 896;
        int rem = idx - t * 896;
        int ww = rem >> 4, cq = rem & 15;
        float4 v = *(const float4*)(Y2 + ((size_t)(t * 8 + b) * HW + h * 56 + ww) * 128
                                       + half * 64 + cq * 4);
        float* dst = &xs[(t * 56 + ww) * 65 + cq * 4];
        dst[0] = v.x; dst[1] = v.y; dst[2] = v.z; dst[3] = v.w;
    }
    __syncthreads();
#pragma unroll
    for (int j = 0; j < 14; ++j) {
        int idx = tid + j * 256;              // c*56 + w
        int c = idx / 56, ww = idx - c * 56;
        float v = 0.f;
        size_t xo = ((size_t)b * 128 + half * 64 + c) * HW + h * 56 + ww;
#pragma unroll
        for (int t = 0; t < 4; ++t) {
            float yv = xs[(t * 56 + ww) * 65 + c];
            v = v + (yv - v) * k;
            bool sp = v >= 1.f;
            size_t o = xo + (size_t)t * NLOC;
            out[o] = (sp ? 1.f : 0.f) + x[o];
            v = sp ? 0.f : v;
        }
    }
}

// ---------------------------------------------------------------------------
extern "C" void kernel_launch(void* const* d_in, const int* in_sizes, int n_in,
                              void* d_out, int out_size, void* d_ws, size_t ws_size,
                              hipStream_t stream) {
    const float* x    = (const float*)d_in[0];
    const float* w1   = (const float*)d_in[1];
    const float* g1   = (const float*)d_in[2];
    const float* be1  = (const float*)d_in[3];
    const float* mu1  = (const float*)d_in[4];
    const float* va1  = (const float*)d_in[5];
    const float* tau1 = (const float*)d_in[6];
    const float* w2   = (const float*)d_in[7];
    const float* g2   = (const float*)d_in[8];
    const float* be2  = (const float*)d_in[9];
    const float* mu2  = (const float*)d_in[10];
    const float* va2  = (const float*)d_in[11];
    const float* tau2 = (const float*)d_in[12];
    float* out = (float*)d_out;

    char* ws = (char*)d_ws;
    signed char* bufA = (signed char*)ws;          // i8 [NE]: Xt then S1
    float* bufY = (float*)(ws + NE);               // fp32 [NE]: Y1 then Y2
    float* sv1  = (float*)(ws + 5 * NE);
    float* sv2  = sv1 + 128;
    signed char* Bs1 = (signed char*)(ws + 5 * NE + 1024);
    signed char* Bs2 = Bs1 + 27 * 16384;

    scale_k<<<128, 128, 0, stream>>>(w1, sv1);
    scale_k<<<128, 128, 0, stream>>>(w2, sv2);
    repack_k<<<36, 256, 0, stream>>>(w1, sv1, Bs1);
    repack_k<<<36, 256, 0, stream>>>(w2, sv2, Bs2);
    xpose_k<<<NIMG * 56, 256, 0, stream>>>(x, bufA);

    conv_mfma_k<<<NIMG * 28, 512, 0, stream>>>(bufA, Bs1, sv1, g1, be1, mu1, va1, bufY);
    plif1_k<<<784, 256, 0, stream>>>(bufY, tau1, bufA);
    conv_mfma_k<<<NIMG * 28, 512, 0, stream>>>(bufA, Bs2, sv2, g2, be2, mu2, va2, bufY);
    plif2_k<<<B_ * 56 * 2, 256, 0, stream>>>(bufY, tau2, x, out);
}

// Round 4
// 203.225 us; speedup vs baseline: 3.8458x; 1.0684x over previous
//
#include <hip/hip_runtime.h>
#include <math.h>

// Dims fixed: T=4, B=8, C=128, H=W=56, mid=128.
#define T_ 4
#define B_ 8
#define C_ 128
#define H_ 56
#define W_ 56
#define NIMG (T_ * B_)              // 32
#define HW (H_ * W_)                // 3136
#define NLOC ((size_t)B_ * C_ * HW) // 3211264 per-t elements
#define NE ((size_t)T_ * NLOC)      // 12845056

typedef __attribute__((ext_vector_type(4))) int   int4v;
typedef __attribute__((ext_vector_type(4))) float float4v;

#define GLOAD_LDS16(gp, lp) \
    __builtin_amdgcn_global_load_lds((const __attribute__((address_space(1))) unsigned int*)(gp), \
                                     (__attribute__((address_space(3))) unsigned int*)(lp), 16, 0, 0)

// ---------------------------------------------------------------------------
// per-co scale: sv[co] = max_{ci,tap}|w[co][ci][tap]| / 127
// ---------------------------------------------------------------------------
__global__ __launch_bounds__(128) void scale_k(const float* __restrict__ w,
                                               float* __restrict__ sv) {
    __shared__ float red[128];
    int co = blockIdx.x, t = threadIdx.x;
    const float* p = w + (size_t)co * 1152 + t * 9;
    float m = 0.f;
#pragma unroll
    for (int j = 0; j < 9; ++j) m = fmaxf(m, fabsf(p[j]));
    red[t] = m; __syncthreads();
    for (int off = 64; off; off >>= 1) {
        if (t < off) red[t] = fmaxf(red[t], red[t + off]);
        __syncthreads();
    }
    if (t == 0) sv[co] = fmaxf(red[0], 1e-20f) / 127.f;
}

// ---------------------------------------------------------------------------
// repack weights -> 27 stages, register-fragment-coalesced layout:
// byte off = stage*16384 + q*4096 + nf*2048 + ks*1024 + fq*256 + fr*16 + i
//   where co = q*32 + nf*16 + fr, ci = (ks*4+fq)*16 + i, stage = tap*3 + split
// Each (stage, q, nf, ks) is a contiguous 1KB wave-load.
// 3-way split: w = s*(q1 + q2/128 + q3/16384)
// ---------------------------------------------------------------------------
__global__ __launch_bounds__(256) void repack_k(const float* __restrict__ w,
                                                const float* __restrict__ sv,
                                                signed char* __restrict__ Bq) {
    int idx = blockIdx.x * 256 + threadIdx.x;
    if (idx >= 9 * 1024) return;
    int tap = idx >> 10;
    int rem = idx & 1023;
    int co = rem >> 3, chunk = rem & 7;
    int ks = chunk >> 2, fq = chunk & 3;
    int q = co >> 5, fr = co & 15, nf = (co >> 4) & 1;
    double s = (double)sv[co];
    union { signed char b[16]; int4v v; } out[3];
#pragma unroll
    for (int e = 0; e < 16; ++e) {
        int ci = chunk * 16 + e;
        double v = (double)w[((size_t)co * 128 + ci) * 9 + tap];
        double q1 = rint(v / s);
        double r1 = v - s * q1;
        double q2 = rint(r1 * 128.0 / s);
        double r2 = r1 - s * q2 * 0.0078125;
        double q3 = rint(r2 * 16384.0 / s);
        out[0].b[e] = (signed char)(int)q1;
        out[1].b[e] = (signed char)(int)q2;
        out[2].b[e] = (signed char)(int)q3;
    }
#pragma unroll
    for (int sp = 0; sp < 3; ++sp) {
        size_t off = (size_t)(tap * 3 + sp) * 16384 + q * 4096 + nf * 2048
                   + ks * 1024 + fq * 256 + fr * 16;
        *(int4v*)(Bq + off) = out[sp].v;
    }
}

// ---------------------------------------------------------------------------
// x fp32 NCHW -> Xt i8 NHWC, ci-slot XOR-swizzled by (w&7):
// byte at px*128 + slot*16 + b holds ci = (slot ^ (px&7))*16 + b
// ---------------------------------------------------------------------------
__global__ __launch_bounds__(256) void xpose_k(const float* __restrict__ x,
                                               signed char* __restrict__ Xt) {
    __shared__ float xs[128][57];
    int n = blockIdx.x / 56, h = blockIdx.x % 56;
    int tid = threadIdx.x;
    const float* xp = x + (size_t)n * 128 * HW + h * 56;
#pragma unroll
    for (int j = 0; j < 7; ++j) {
        int idx = tid + j * 256;              // 0..1791 = c*14 + wq
        int c = idx / 14, wq = idx - c * 14;
        float4 v = *(const float4*)(xp + (size_t)c * HW + wq * 4);
        xs[c][wq * 4 + 0] = v.x; xs[c][wq * 4 + 1] = v.y;
        xs[c][wq * 4 + 2] = v.z; xs[c][wq * 4 + 3] = v.w;
    }
    __syncthreads();
    signed char* Op = Xt + ((size_t)n * HW + h * 56) * 128;
#pragma unroll
    for (int j = 0; j < 2; ++j) {
        int idx = tid + j * 256;              // 0..447 = ww*8 + slot
        if (idx < 448) {
            int ww = idx >> 3, sl = idx & 7;
            int cg = sl ^ (ww & 7);
            union { signed char b[16]; int4v v; } u;
#pragma unroll
            for (int e = 0; e < 16; ++e)
                u.b[e] = (xs[cg * 16 + e][ww] >= 0.5f) ? 1 : 0;
            *(int4v*)(Op + ww * 128 + sl * 16) = u.v;
        }
    }
}

// ---------------------------------------------------------------------------
// conv3x3 SAME + BN, i8 MFMA, barrier-free K-loop.
// Block: 256 thr / 4 waves = 4 co-quarters, ONE output row.
// A (3 rows) staged once in LDS. B direct L2->reg, 4-deep ring, prefetch +2.
// 3 int accumulators (per split), folded once in epilogue.
// ---------------------------------------------------------------------------
__global__ __launch_bounds__(256, 2) void conv_mfma_k(
        const signed char* __restrict__ Xt,   // i8 NHWC swizzled [32][3136][128]
        const signed char* __restrict__ Bq,   // 27 stages x 16KB, frag-coalesced
        const float* __restrict__ sv,
        const float* __restrict__ gamma, const float* __restrict__ beta,
        const float* __restrict__ mean,  const float* __restrict__ var,
        float* __restrict__ Y) {              // fp32 NHWC
    __shared__ signed char aA[3 * 8192];      // rows h-1,h,h+1 x 64px x 128ci

    const int tid = threadIdx.x;
    const int lane = tid & 63;
    const int q = tid >> 6;                   // wave = co-quarter
    const int fr = lane & 15, fq = lane >> 4;
    const int img = blockIdx.x / 56;
    const int h = blockIdx.x % 56;

    // ---- prologue: stage A rows (clamped; masked at use) ----
    const signed char* XtN = Xt + (size_t)img * HW * 128;
#pragma unroll
    for (int i = 0; i < 3; ++i) {
        int hh = h - 1 + i;
        hh = hh < 0 ? 0 : (hh > 55 ? 55 : hh);
        const char* src = (const char*)(XtN + (size_t)hh * 7168);
        GLOAD_LDS16(src + tid * 16, (char*)aA + i * 8192 + tid * 16);
        GLOAD_LDS16(src + 4096 + tid * 16, (char*)aA + i * 8192 + 4096 + tid * 16);
    }

    const signed char* bqq = Bq + q * 4096 + fq * 256 + fr * 16;
    int4v bb[4][4];                            // ring: stage&3, frag j=nf*2+ks
#pragma unroll
    for (int s = 0; s < 2; ++s)
#pragma unroll
        for (int j = 0; j < 4; ++j)
            bb[s][j] = *(const int4v*)(bqq + (size_t)s * 16384 + j * 1024);

    asm volatile("s_waitcnt vmcnt(0)" ::: "memory");
    __builtin_amdgcn_sched_barrier(0);
    __builtin_amdgcn_s_barrier();              // A ready; no further barriers

    const int4v zi = (int4v){0, 0, 0, 0};
    int4v acc[3][4][2];
#pragma unroll
    for (int sp = 0; sp < 3; ++sp)
#pragma unroll
        for (int m = 0; m < 4; ++m) {
            acc[sp][m][0] = zi; acc[sp][m][1] = zi;
        }

    // ---- K-loop: 9 taps x 3 splits, no barriers, no waitcnt drains ----
#pragma unroll
    for (int tap = 0; tap < 9; ++tap) {
        const int dh = tap / 3, dw = tap % 3;
        const bool hok = (dh == 1) || (dh == 0 ? (h > 0) : (h < 55));
        int4v a[4][2];
#pragma unroll
        for (int m = 0; m < 4; ++m) {
            int px = m * 16 + fr + dw - 1;
            bool ok = hok && ((unsigned)px < 56u);
            int pxc = ok ? px : 0;
            const signed char* base = aA + dh * 8192 + pxc * 128;
#pragma unroll
            for (int ks = 0; ks < 2; ++ks) {
                int sl = (ks * 4 + fq) ^ (pxc & 7);
                int4v v = *(const int4v*)(base + sl * 16);
                a[m][ks] = ok ? v : zi;
            }
        }
#pragma unroll
        for (int sp = 0; sp < 3; ++sp) {
            const int s = tap * 3 + sp;
            if (s + 2 < 27) {                  // prefetch stage s+2
#pragma unroll
                for (int j = 0; j < 4; ++j)
                    bb[(s + 2) & 3][j] =
                        *(const int4v*)(bqq + (size_t)(s + 2) * 16384 + j * 1024);
            }
#pragma unroll
            for (int ks = 0; ks < 2; ++ks)
#pragma unroll
                for (int m = 0; m < 4; ++m) {
                    acc[sp][m][0] = __builtin_amdgcn_mfma_i32_16x16x64_i8(
                        a[m][ks], bb[s & 3][ks], acc[sp][m][0], 0, 0, 0);
                    acc[sp][m][1] = __builtin_amdgcn_mfma_i32_16x16x64_i8(
                        a[m][ks], bb[s & 3][2 + ks], acc[sp][m][1], 0, 0, 0);
                }
        }
    }

    // ---- epilogue: fold splits + BN + store ----
    float* Yp = Y + ((size_t)img * HW + h * 56) * 128;
#pragma unroll
    for (int nf = 0; nf < 2; ++nf) {
        int co = q * 32 + nf * 16 + fr;
        float s = sv[co];
        float iv = gamma[co] / sqrtf(var[co] + 1e-5f);
        float mul = s * iv;
        float bs = beta[co] - mean[co] * iv;
#pragma unroll
        for (int m = 0; m < 4; ++m)
#pragma unroll
            for (int r = 0; r < 4; ++r) {
                int ww = m * 16 + fq * 4 + r;
                if (ww < 56) {
                    float val = (float)acc[0][m][nf][r]
                              + (float)acc[1][m][nf][r] * 0.0078125f
                              + (float)acc[2][m][nf][r] * 6.103515625e-05f;
                    Yp[(size_t)ww * 128 + co] = fmaf(val, mul, bs);
                }
            }
    }
}

// ---------------------------------------------------------------------------
// PLIF layer1: Y fp32 NHWC -> spikes i8 NHWC (swizzled, conv2 input)
// ---------------------------------------------------------------------------
__global__ __launch_bounds__(256) void plif1_k(const float* __restrict__ Y,
                                               const float* __restrict__ wp,
                                               signed char* __restrict__ S) {
    int gid = blockIdx.x * 256 + threadIdx.x;     // 0..200703
    int cg = gid & 7;
    int pix = gid >> 3;                           // b*3136 + hw
    int w = (pix % HW) % 56;
    float k = 1.f / (1.f + expf(-wp[0]));
    float v[16];
#pragma unroll
    for (int e = 0; e < 16; ++e) v[e] = 0.f;
    size_t base = (size_t)pix * 128 + cg * 16;
    size_t obase = (size_t)pix * 128 + ((cg ^ (w & 7)) << 4);
#pragma unroll
    for (int t = 0; t < 4; ++t) {
        const float* yp = Y + (size_t)t * NLOC + base;
        union { signed char b[16]; int4v iv; } u;
#pragma unroll
        for (int e4 = 0; e4 < 4; ++e4) {
            float4 xv = *(const float4*)(yp + e4 * 4);
            float xe[4] = {xv.x, xv.y, xv.z, xv.w};
#pragma unroll
            for (int j = 0; j < 4; ++j) {
                int e = e4 * 4 + j;
                v[e] = v[e] + (xe[j] - v[e]) * k;
                bool sp = v[e] >= 1.f;
                u.b[e] = sp ? 1 : 0;
                v[e] = sp ? 0.f : v[e];
            }
        }
        *(int4v*)(S + (size_t)t * NLOC + obase) = u.iv;
    }
}

// ---------------------------------------------------------------------------
// PLIF layer2 + residual: Y2 fp32 NHWC + x fp32 NCHW -> out fp32 NCHW
// ---------------------------------------------------------------------------
__global__ __launch_bounds__(256) void plif2_k(const float* __restrict__ Y2,
                                               const float* __restrict__ wp,
                                               const float* __restrict__ x,
                                               float* __restrict__ out) {
    __shared__ float xs[4 * 56 * 65];
    int bid = blockIdx.x;
    int half = bid & 1;
    int bh = bid >> 1;
    int b = bh / 56, h = bh % 56;
    int tid = threadIdx.x;
    float k = 1.f / (1.f + expf(-wp[0]));
#pragma unroll
    for (int j = 0; j < 14; ++j) {
        int idx = tid + j * 256;              // 0..3583
        int t = idx / 896;
        int rem = idx - t * 896;
        int ww = rem >> 4, cq = rem & 15;
        float4 v = *(const float4*)(Y2 + ((size_t)(t * 8 + b) * HW + h * 56 + ww) * 128
                                       + half * 64 + cq * 4);
        float* dst = &xs[(t * 56 + ww) * 65 + cq * 4];
        dst[0] = v.x; dst[1] = v.y; dst[2] = v.z; dst[3] = v.w;
    }
    __syncthreads();
#pragma unroll
    for (int j = 0; j < 14; ++j) {
        int idx = tid + j * 256;              // c*56 + w
        int c = idx / 56, ww = idx - c * 56;
        float v = 0.f;
        size_t xo = ((size_t)b * 128 + half * 64 + c) * HW + h * 56 + ww;
#pragma unroll
        for (int t = 0; t < 4; ++t) {
            float yv = xs[(t * 56 + ww) * 65 + c];
            v = v + (yv - v) * k;
            bool sp = v >= 1.f;
            size_t o = xo + (size_t)t * NLOC;
            out[o] = (sp ? 1.f : 0.f) + x[o];
            v = sp ? 0.f : v;
        }
    }
}

// ---------------------------------------------------------------------------
extern "C" void kernel_launch(void* const* d_in, const int* in_sizes, int n_in,
                              void* d_out, int out_size, void* d_ws, size_t ws_size,
                              hipStream_t stream) {
    const float* x    = (const float*)d_in[0];
    const float* w1   = (const float*)d_in[1];
    const float* g1   = (const float*)d_in[2];
    const float* be1  = (const float*)d_in[3];
    const float* mu1  = (const float*)d_in[4];
    const float* va1  = (const float*)d_in[5];
    const float* tau1 = (const float*)d_in[6];
    const float* w2   = (const float*)d_in[7];
    const float* g2   = (const float*)d_in[8];
    const float* be2  = (const float*)d_in[9];
    const float* mu2  = (const float*)d_in[10];
    const float* va2  = (const float*)d_in[11];
    const float* tau2 = (const float*)d_in[12];
    float* out = (float*)d_out;

    char* ws = (char*)d_ws;
    signed char* bufA = (signed char*)ws;          // i8 [NE]: Xt then S1
    float* bufY = (float*)(ws + NE);               // fp32 [NE]: Y1 then Y2
    float* sv1  = (float*)(ws + 5 * NE);
    float* sv2  = sv1 + 128;
    signed char* Bq1 = (signed char*)(ws + 5 * NE + 1024);
    signed char* Bq2 = Bq1 + 27 * 16384;

    scale_k<<<128, 128, 0, stream>>>(w1, sv1);
    scale_k<<<128, 128, 0, stream>>>(w2, sv2);
    repack_k<<<36, 256, 0, stream>>>(w1, sv1, Bq1);
    repack_k<<<36, 256, 0, stream>>>(w2, sv2, Bq2);
    xpose_k<<<NIMG * 56, 256, 0, stream>>>(x, bufA);

    conv_mfma_k<<<NIMG * 56, 256, 0, stream>>>(bufA, Bq1, sv1, g1, be1, mu1, va1, bufY);
    plif1_k<<<784, 256, 0, stream>>>(bufY, tau1, bufA);
    conv_mfma_k<<<NIMG * 56, 256, 0, stream>>>(bufA, Bq2, sv2, g2, be2, mu2, va2, bufY);
    plif2_k<<<B_ * 56 * 2, 256, 0, stream>>>(bufY, tau2, x, out);
}